// Round 1
// baseline (395.211 us; speedup 1.0000x reference)
//
#include <hip/hip_runtime.h>

// Reference computes: lam = max(0, -q/Q) with q=0, Q=1 => lam = zeros(10),
// broadcast over batch => output is 2,000,000 x 10 float32 zeros (80 MB).
// Input x is unused. Harness poisons d_out with 0xAA before each timed call,
// so every launch must rewrite the zeros. Pure HBM-write-bound: target ~13-20us.

__global__ __launch_bounds__(256) void zero_fill_f4(float4* __restrict__ out,
                                                    long long n4) {
    long long i = (long long)blockIdx.x * blockDim.x + threadIdx.x;
    long long stride = (long long)gridDim.x * blockDim.x;
    const float4 z = make_float4(0.f, 0.f, 0.f, 0.f);
    for (; i < n4; i += stride) {
        out[i] = z;
    }
}

extern "C" void kernel_launch(void* const* d_in, const int* in_sizes, int n_in,
                              void* d_out, int out_size, void* d_ws, size_t ws_size,
                              hipStream_t stream) {
    (void)d_in; (void)in_sizes; (void)n_in; (void)d_ws; (void)ws_size;
    // out_size = 20,000,000 floats, divisible by 4 -> 5,000,000 float4 stores.
    long long n4 = (long long)out_size / 4;
    int block = 256;
    // One float4 per thread, single pass: 5,000,000 / 256 = 19532 blocks.
    long long grid = (n4 + block - 1) / block;
    if (grid > 1048576) grid = 1048576;  // safety clamp; grid-stride covers rest
    zero_fill_f4<<<(int)grid, block, 0, stream>>>((float4*)d_out, n4);
}